// Round 3
// baseline (654.878 us; speedup 1.0000x reference)
//
#include <hip/hip_runtime.h>
#include <hip/hip_bf16.h>
#include <stdint.h>

typedef unsigned short u16;
typedef __attribute__((ext_vector_type(8))) __bf16 bf16x8;
typedef __attribute__((ext_vector_type(4))) float floatx4;
typedef __attribute__((ext_vector_type(8))) unsigned short us8;
typedef __attribute__((ext_vector_type(4))) unsigned short us4;

#define TT 4096
#define BB 4
#define DM 1024
#define ROWS (TT * BB)      // 16384 flattened (t,b) rows
#define CHUNK 128           // timesteps per chunk
#define CR (CHUNK * BB)     // 512 rows per chunk
#define NC (TT / CHUNK)     // 32 chunks
#define MB (1024l * 1024l)

__device__ __forceinline__ float b2f(u16 x) {
  union { unsigned int u; float f; } v; v.u = ((unsigned int)x) << 16; return v.f;
}
__device__ __forceinline__ u16 f2b(float f) {
  union { float f; unsigned int u; } v; v.f = f;
  unsigned int r = v.u + 0x7fffu + ((v.u >> 16) & 1u);   // RNE
  return (u16)(r >> 16);
}

// ---- dtype sniffer: flag=1 if input stream is bf16, 0 if fp32.
// bf16 data: even-indexed u16s are real values, exponent field near 127.
// fp32 data: even-indexed u16s are low mantissa bits, exponent field ~uniform.
__global__ void k_sniff(const u16* __restrict__ x, int* __restrict__ flag) {
  if (blockIdx.x == 0 && threadIdx.x == 0) {
    int cnt = 0;
    for (int i = 0; i < 2048; ++i) {
      u16 u = x[2 * i];
      int e = (u >> 7) & 0xFF;
      if (e >= 100 && e <= 140) ++cnt;
    }
    *flag = (cnt >= 1024) ? 1 : 0;
  }
}

// ---- canonicalize input to bf16 (copy if bf16, round if fp32)
__global__ __launch_bounds__(256) void k_convert(const void* __restrict__ src,
                                                 u16* __restrict__ dst,
                                                 const int* __restrict__ flag, long n) {
  long i = ((long)blockIdx.x * 256 + threadIdx.x) * 4;
  if (i >= n) return;
  if (*flag) {
    *(us4*)(dst + i) = *(const us4*)((const u16*)src + i);
  } else {
    const float* s = (const float*)src;
    us4 o;
#pragma unroll
    for (int e = 0; e < 4; ++e) o[e] = f2b(s[i + e]);
    *(us4*)(dst + i) = o;
  }
}

// ---- emit output in the flagged dtype
__global__ __launch_bounds__(256) void k_emit(const u16* __restrict__ Yc, void* __restrict__ out,
                                              const int* __restrict__ flag, long n) {
  long i = ((long)blockIdx.x * 256 + threadIdx.x) * 4;
  if (i >= n) return;
  us4 v = *(const us4*)(Yc + i);
  if (*flag) {
    *(us4*)((u16*)out + i) = v;
  } else {
    float* o = (float*)out;
#pragma unroll
    for (int e = 0; e < 4; ++e) o[i + e] = b2f(v[e]);
  }
}

// async global->LDS, 16B per lane; LDS dest must be wave-uniform base (+lane*16 implicit)
__device__ __forceinline__ void ldsg16(const u16* g, u16* l) {
  auto gp = reinterpret_cast<__attribute__((address_space(1))) void*>(
      reinterpret_cast<uintptr_t>(const_cast<u16*>(g)));
  auto lp = reinterpret_cast<__attribute__((address_space(3))) void*>(
      (unsigned int)reinterpret_cast<uintptr_t>(l));   // low 32 bits of generic LDS ptr = ds offset
  __builtin_amdgcn_global_load_lds(gp, lp, 16, 0, 0);
}

// 128x128 output tile, 256 threads (4 waves, each 64x64 as 4x4 of 16x16x32 mfma).
// Computes acc += A(128 rows, k-contig, lda) . B^T(128 rows, k-contig, ldb). K % 32 == 0.
__device__ __forceinline__ void gemm_core(
    const u16* __restrict__ A, int lda,
    const u16* __restrict__ B, int ldb,
    int K, u16* sA, u16* sB, floatx4 acc[4][4])
{
  const int t = threadIdx.x;
  const int w = t >> 6;
  const int lane = t & 63;
  const int m16 = lane & 15;
  const int quad = lane >> 4;
  const int wm = w >> 1, wn = w & 1;
  const u16* ga = A + (long)(t >> 2) * lda + (t & 3) * 8;   // row t/4, colgroup t%4
  const u16* gb = B + (long)(t >> 2) * ldb + (t & 3) * 8;
  const long a64 = 64l * lda, b64 = 64l * ldb;
  u16* lA = sA + w * 512;        // wave-uniform LDS staging base (bytes: w*1024)
  u16* lB = sB + w * 512;
  const u16* rA = sA + (wm * 64 + m16) * 32 + quad * 8;   // frag read base
  const u16* rB = sB + (wn * 64 + m16) * 32 + quad * 8;
  for (int k0 = 0; k0 < K; k0 += 32) {
    __syncthreads();                       // prev iter's ds_reads done before overwrite
    ldsg16(ga, lA);                        // rows 0..63 of A tile
    ldsg16(ga + a64, lA + 2048);           // rows 64..127
    ldsg16(gb, lB);
    ldsg16(gb + b64, lB + 2048);
    ga += 32; gb += 32;
    __syncthreads();                       // compiler drains vmcnt before s_barrier
    bf16x8 af[4], bfr[4];
#pragma unroll
    for (int i = 0; i < 4; ++i) af[i]  = *(const bf16x8*)(rA + i * 16 * 32);
#pragma unroll
    for (int i = 0; i < 4; ++i) bfr[i] = *(const bf16x8*)(rB + i * 16 * 32);
#pragma unroll
    for (int im = 0; im < 4; ++im)
#pragma unroll
      for (int in = 0; in < 4; ++in)
        acc[im][in] = __builtin_amdgcn_mfma_f32_16x16x32_bf16(af[im], bfr[in], acc[im][in], 0, 0, 0);
  }
}

// ---- projections: Y = elu?(X @ W^T); mode 0 plain, 1 elu+1, 2 transposed store (V -> Vt)
__global__ __launch_bounds__(256) void k_proj(
    const u16* __restrict__ X, const u16* __restrict__ Wt, u16* __restrict__ Y, int mode)
{
  __shared__ __align__(16) u16 sA[4096];
  __shared__ __align__(16) u16 sB[4096];
  floatx4 acc[4][4] = {};
  const int n0 = blockIdx.x * 128;
  const int m0 = blockIdx.y * 128;
  gemm_core(X + (long)m0 * DM, DM, Wt + (long)n0 * DM, DM, DM, sA, sB, acc);
  const int t = threadIdx.x, lane = t & 63, w = t >> 6;
  const int wm = w >> 1, wn = w & 1, quad = lane >> 4, c16 = lane & 15;
#pragma unroll
  for (int im = 0; im < 4; ++im) {
#pragma unroll
    for (int in = 0; in < 4; ++in) {
      const int gc = n0 + wn * 64 + in * 16 + c16;
      const int gr = m0 + wm * 64 + im * 16 + quad * 4;
      floatx4 v = acc[im][in];
      if (mode == 2) {
        us4 o;
#pragma unroll
        for (int e = 0; e < 4; ++e) o[e] = f2b(v[e]);
        *(us4*)(Y + (long)gc * ROWS + gr) = o;      // Vt[model][row], 8B store
      } else {
#pragma unroll
        for (int e = 0; e < 4; ++e) {
          float u = v[e];
          if (mode == 1) u = u > 0.f ? u + 1.f : __expf(u);   // elu(u)+1
          Y[(long)(gr + e) * DM + gc] = f2b(u);
        }
      }
    }
  }
}

// ---- K[ROWS][DM] -> Kt[DM][ROWS], 8x8 in-register blocks
__global__ __launch_bounds__(256) void k_transpose(const u16* __restrict__ src, u16* __restrict__ dst)
{
  const int t = threadIdx.x;
  const int sx = t & 15, sy = t >> 4;
  const long r0 = (long)blockIdx.x * 128 + sy * 8;   // source row
  const long c0 = (long)blockIdx.y * 128 + sx * 8;   // source col
  us8 r[8];
#pragma unroll
  for (int v = 0; v < 8; ++v) r[v] = *(const us8*)(src + (r0 + v) * DM + c0);
#pragma unroll
  for (int u = 0; u < 8; ++u) {
    us8 o;
#pragma unroll
    for (int v = 0; v < 8; ++v) o[v] = r[v][u];
    *(us8*)(dst + (c0 + u) * ROWS + r0) = o;
  }
}

// ---- per-chunk K column sums: cs[j][b][i]
__global__ __launch_bounds__(256) void k_cksum(const u16* __restrict__ Kp, float* __restrict__ cs)
{
  const int id = blockIdx.x * 256 + threadIdx.x;      // 131072 = 32*4*1024
  const int i = id & 1023, b = (id >> 10) & 3, j = id >> 12;
  const u16* p = Kp + ((long)j * CR + b) * DM + i;
  float a = 0.f;
#pragma unroll 8
  for (int tl = 0; tl < CHUNK; ++tl) a += b2f(p[(long)tl * BB * DM]);
  cs[id] = a;
}

// ---- z[row][i] = inclusive per-batch cumsum of k over time (bf16 store, fp32 running)
__global__ __launch_bounds__(256) void k_zfill(const u16* __restrict__ Kp,
                                               const float* __restrict__ cs,
                                               u16* __restrict__ z)
{
  const int id = blockIdx.x * 256 + threadIdx.x;
  const int i = id & 1023, b = (id >> 10) & 3, j = id >> 12;
  float a = 0.f;
  for (int j2 = 0; j2 < j; ++j2) a += cs[j2 * 4096 + b * 1024 + i];
  const u16* p = Kp + ((long)j * CR + b) * DM + i;
  u16* q = z + ((long)j * CR + b) * DM + i;
  for (int tl = 0; tl < CHUNK; ++tl) {
    a += b2f(p[(long)tl * BB * DM]);
    q[(long)tl * BB * DM] = f2b(a);
  }
}

// ---- per-chunk G[j][m][i] = sum_{rows r in chunk} V[r][m] K[r][i]  (stored bf16)
__global__ __launch_bounds__(256) void k_gemm_g(
    const u16* __restrict__ Vt, const u16* __restrict__ Kt, u16* __restrict__ G)
{
  __shared__ __align__(16) u16 sA[4096];
  __shared__ __align__(16) u16 sB[4096];
  floatx4 acc[4][4] = {};
  const int j = blockIdx.z;
  const int n0 = blockIdx.x * 128;   // key index i
  const int m0 = blockIdx.y * 128;   // model index m
  gemm_core(Vt + (long)m0 * ROWS + j * CR, ROWS,
            Kt + (long)n0 * ROWS + j * CR, ROWS, CR, sA, sB, acc);
  const int t = threadIdx.x, lane = t & 63, w = t >> 6;
  const int wm = w >> 1, wn = w & 1, quad = lane >> 4, c16 = lane & 15;
  u16* Gj = G + (long)j * DM * DM;
#pragma unroll
  for (int im = 0; im < 4; ++im)
#pragma unroll
    for (int in = 0; in < 4; ++in) {
      const int gc = n0 + wn * 64 + in * 16 + c16;
      const int gr = m0 + wm * 64 + im * 16 + quad * 4;
      floatx4 v = acc[im][in];
#pragma unroll
      for (int e = 0; e < 4; ++e) Gj[(long)(gr + e) * DM + gc] = f2b(v[e]);
    }
}

// ---- in-place exclusive prefix over chunks: G[j] <- sum_{j'<j} G[j']  (per element)
__global__ __launch_bounds__(256) void k_prefix(u16* __restrict__ G)
{
  const long id = (long)blockIdx.x * 256 + threadIdx.x;   // 1048576
  float a = 0.f;
#pragma unroll
  for (int j = 0; j < NC; ++j) {
    u16* p = G + (long)j * DM * DM + id;
    float g = b2f(*p);
    *p = f2b(a);
    a += g;
  }
}

// ---- intra-chunk scores P[j][r][c] = q_r . k_c, masked to c <= (r|3), bf16
__global__ __launch_bounds__(256) void k_scores(
    const u16* __restrict__ Q, const u16* __restrict__ Kp, u16* __restrict__ P)
{
  __shared__ __align__(16) u16 sA[4096];
  __shared__ __align__(16) u16 sB[4096];
  floatx4 acc[4][4] = {};
  const int j = blockIdx.z;
  const int n0 = blockIdx.x * 128;   // col (t',b') in chunk
  const int m0 = blockIdx.y * 128;   // row (t,b) in chunk
  gemm_core(Q + ((long)j * CR + m0) * DM, DM,
            Kp + ((long)j * CR + n0) * DM, DM, DM, sA, sB, acc);
  const int t = threadIdx.x, lane = t & 63, w = t >> 6;
  const int wm = w >> 1, wn = w & 1, quad = lane >> 4, c16 = lane & 15;
  u16* Pj = P + (long)j * CR * CR;
#pragma unroll
  for (int im = 0; im < 4; ++im)
#pragma unroll
    for (int in = 0; in < 4; ++in) {
      const int gc = n0 + wn * 64 + in * 16 + c16;
      const int gr = m0 + wm * 64 + im * 16 + quad * 4;   // rows gr..gr+3 share t-block
      const bool valid = (gc <= gr + 3);                  // t' <= t (diagonal included)
      floatx4 v = acc[im][in];
#pragma unroll
      for (int e = 0; e < 4; ++e)
        Pj[(long)(gr + e) * CR + gc] = valid ? f2b(v[e]) : (u16)0;
    }
}

// ---- denom[row] = q_row . z_row  (one wave per row)
__global__ __launch_bounds__(256) void k_denom(
    const u16* __restrict__ Q, const u16* __restrict__ z, float* __restrict__ denom)
{
  const int w = threadIdx.x >> 6, lane = threadIdx.x & 63;
  const long row = (long)blockIdx.x * 4 + w;
  const u16* q = Q + row * DM;
  const u16* zz = z + row * DM;
  float s = 0.f;
#pragma unroll
  for (int p = 0; p < 2; ++p) {
    const int off = lane * 8 + p * 512;
    us8 q8 = *(const us8*)(q + off);
    us8 z8 = *(const us8*)(zz + off);
#pragma unroll
    for (int e = 0; e < 8; ++e) s += b2f(q8[e]) * b2f(z8[e]);
  }
#pragma unroll
  for (int d = 32; d > 0; d >>= 1) s += __shfl_down(s, d, 64);
  if (lane == 0) denom[row] = s;
}

// ---- y = (P @ V + Q @ S_chunkstart) / denom  (writes canonical bf16 Yc)
__global__ __launch_bounds__(256) void k_out(
    const u16* __restrict__ P, const u16* __restrict__ Vt,
    const u16* __restrict__ Q, const u16* __restrict__ St,
    const float* __restrict__ denom, u16* __restrict__ Y)
{
  __shared__ __align__(16) u16 sA[4096];
  __shared__ __align__(16) u16 sB[4096];
  floatx4 acc[4][4] = {};
  const int j = blockIdx.z;
  const int n0 = blockIdx.x * 128;   // model col
  const int m0 = blockIdx.y * 128;   // row in chunk
  gemm_core(P + (long)j * CR * CR + (long)m0 * CR, CR,
            Vt + (long)n0 * ROWS + j * CR, ROWS, CR, sA, sB, acc);
  gemm_core(Q + ((long)j * CR + m0) * DM, DM,
            St + (long)j * DM * DM + (long)n0 * DM, DM, DM, sA, sB, acc);
  const int t = threadIdx.x, lane = t & 63, w = t >> 6;
  const int wm = w >> 1, wn = w & 1, quad = lane >> 4, c16 = lane & 15;
#pragma unroll
  for (int im = 0; im < 4; ++im)
#pragma unroll
    for (int in = 0; in < 4; ++in) {
      const int gc = n0 + wn * 64 + in * 16 + c16;
      const int grl = m0 + wm * 64 + im * 16 + quad * 4;
      const long gr = (long)j * CR + grl;
      floatx4 v = acc[im][in];
#pragma unroll
      for (int e = 0; e < 4; ++e) {
        const float d = denom[gr + e];
        Y[(gr + e) * DM + gc] = f2b(v[e] / d);
      }
    }
}

extern "C" void kernel_launch(void* const* d_in, const int* in_sizes, int n_in,
                              void* d_out, int out_size, void* d_ws, size_t ws_size,
                              hipStream_t stream)
{
  char* ws = (char*)d_ws;   // total ~230.6 MiB with lifetime overlays
  u16*  xc  = (u16*)(ws);              // region A [32M]: xc, later z
  u16*  z   = (u16*)(ws);
  u16*  Q   = (u16*)(ws + 32 * MB);    // region B [32M]
  u16*  K   = (u16*)(ws + 64 * MB);    // region C [32M]: K, later Yc
  u16*  Yc  = (u16*)(ws + 64 * MB);
  u16*  Kt  = (u16*)(ws + 96 * MB);    // region D [32M]: Kt, later P (16M)
  u16*  P   = (u16*)(ws + 96 * MB);
  u16*  Vt  = (u16*)(ws + 128 * MB);   // region E [32M]
  u16*  G   = (u16*)(ws + 160 * MB);   // region F [64M] (becomes St after k_prefix)
  u16*  Wqc = (u16*)(ws + 224 * MB);   // 2M each
  u16*  Wkc = (u16*)(ws + 226 * MB);
  u16*  Wvc = (u16*)(ws + 228 * MB);
  float* cs = (float*)(ws + 230 * MB);           // 512K
  float* dn = (float*)(ws + 230 * MB + 524288);  // 64K
  int* flag = (int*)(ws + 230 * MB + 524288 + 65536);

  dim3 blk(256);
  k_sniff<<<1, 64, 0, stream>>>((const u16*)d_in[0], flag);
  k_convert<<<16384, blk, 0, stream>>>(d_in[0], xc, flag, (long)ROWS * DM);
  k_convert<<<1024, blk, 0, stream>>>(d_in[1], Wqc, flag, (long)DM * DM);
  k_convert<<<1024, blk, 0, stream>>>(d_in[2], Wkc, flag, (long)DM * DM);
  k_convert<<<1024, blk, 0, stream>>>(d_in[3], Wvc, flag, (long)DM * DM);
  k_proj<<<dim3(8, 128), blk, 0, stream>>>(xc, Wqc, Q, 1);
  k_proj<<<dim3(8, 128), blk, 0, stream>>>(xc, Wkc, K, 1);
  k_proj<<<dim3(8, 128), blk, 0, stream>>>(xc, Wvc, Vt, 2);
  k_transpose<<<dim3(128, 8), blk, 0, stream>>>(K, Kt);
  k_cksum<<<dim3(512), blk, 0, stream>>>(K, cs);
  k_zfill<<<dim3(512), blk, 0, stream>>>(K, cs, z);       // z overlays dead xc
  k_gemm_g<<<dim3(8, 8, 32), blk, 0, stream>>>(Vt, Kt, G);
  k_prefix<<<dim3(4096), blk, 0, stream>>>(G);
  k_scores<<<dim3(4, 4, 32), blk, 0, stream>>>(Q, K, P);  // P overlays dead Kt
  k_denom<<<dim3(4096), blk, 0, stream>>>(Q, z, dn);
  k_out<<<dim3(8, 4, 32), blk, 0, stream>>>(P, Vt, Q, G, dn, Yc);  // Yc overlays dead K
  k_emit<<<16384, blk, 0, stream>>>(Yc, d_out, flag, (long)ROWS * DM);
}